// Round 4
// baseline (1385.038 us; speedup 1.0000x reference)
//
#include <hip/hip_runtime.h>

#define B 128
#define C 32
#define HH 16
#define V 4096
#define CHUNK 128

// ---------------- helpers ----------------

__device__ __forceinline__ float cubicw(float t) {
    // PyTorch bicubic kernel, a = -0.75
    float at = fabsf(t);
    float at2 = at * at, at3 = at2 * at;
    if (at <= 1.f) return 1.25f * at3 - 2.25f * at2 + 1.f;
    if (at < 2.f)  return -0.75f * at3 + 3.75f * at2 - 6.f * at + 3.f;
    return 0.f;
}

// ---------------- kernels ----------------

__global__ void init_kernel(const float* __restrict__ feat, float* __restrict__ f_rest,
                            float* __restrict__ f_hat) {
    int i = blockIdx.x * 256 + threadIdx.x;
    if (i < B * C * HH * HH) { f_rest[i] = feat[i]; f_hat[i] = 0.f; }
}

__global__ void c2_kernel(const float* __restrict__ cb, double* __restrict__ c2) {
    int v = blockIdx.x * 256 + threadIdx.x;
    if (v < V) {
        const float* p = cb + v * C;
        double s = 0.0;
        #pragma unroll
        for (int j = 0; j < C; ++j) { double d = (double)p[j]; s = fma(d, d, s); }
        c2[v] = s;
    }
}

// area (adaptive-avg-pool) downsample: [B,C,16,16] -> [B,C,pn,pn] (stage-0 z only)
__global__ void area_down_kernel(const float* __restrict__ src, float* __restrict__ dst, int pn) {
    int i = blockIdx.x * blockDim.x + threadIdx.x;
    int npx = pn * pn;
    int total = B * C * npx;
    if (i >= total) return;
    int x = i % pn, y = (i / pn) % pn, bc = i / npx;
    int sh = (y * HH) / pn, eh = ((y + 1) * HH + pn - 1) / pn;
    int sw = (x * HH) / pn, ew = ((x + 1) * HH + pn - 1) / pn;
    const float* p = src + bc * (HH * HH);
    float s = 0.f;
    for (int yy = sh; yy < eh; ++yy)
        for (int xx = sw; xx < ew; ++xx) s += p[yy * HH + xx];
    dst[i] = s * (1.f / (float)((eh - sh) * (ew - sw)));
}

// ---- quantization scan: TPT tokens per thread over a codebook segment ----
// __launch_bounds__(256,2): 2 waves/EU min -> 256-VGPR budget, keeps zd register-resident.
template<int TPT>
__global__ __launch_bounds__(256, 2) void quantize_scan_kernel(
    const float* __restrict__ z, const float* __restrict__ cb,
    const double* __restrict__ c2, double* __restrict__ pscore,
    int* __restrict__ pidx, int npx, int nseg, int nblk_tok)
{
    int total = B * npx;
    int tid = threadIdx.x;
    int tb  = blockIdx.x % nblk_tok;
    int seg = blockIdx.x / nblk_tok;
    int cps = V / nseg;
    int seg_base = seg * cps;

    double zd[TPT][C];
    int tokv[TPT];
    #pragma unroll
    for (int t = 0; t < TPT; ++t) {
        int tok = tb * (256 * TPT) + t * 256 + tid;
        tokv[t] = tok;
        int tokc = min(tok, total - 1);
        int b = tokc / npx, n = tokc - b * npx;
        #pragma unroll
        for (int c = 0; c < C; ++c) zd[t][c] = (double)z[(b * C + c) * npx + n];
    }

    __shared__ alignas(16) double lcb[CHUNK * C];
    __shared__ double lc2[CHUNK];

    double best[TPT]; int bi[TPT];
    #pragma unroll
    for (int t = 0; t < TPT; ++t) { best[t] = 1e300; bi[t] = 0; }

    for (int ch = 0; ch < cps; ch += CHUNK) {
        __syncthreads();
        const float* src = cb + (size_t)(seg_base + ch) * C;
        #pragma unroll
        for (int k = 0; k < (CHUNK * C) / 256; ++k) {
            int e = tid + k * 256;
            lcb[e] = (double)src[e];
        }
        if (tid < CHUNK) lc2[tid] = c2[seg_base + ch + tid];
        __syncthreads();

        for (int v = 0; v < CHUNK; ++v) {
            double aA[TPT], aB[TPT];
            #pragma unroll
            for (int t = 0; t < TPT; ++t) { aA[t] = 0.0; aB[t] = 0.0; }
            #pragma unroll
            for (int j2 = 0; j2 < 8; ++j2) {
                double2 ca = *reinterpret_cast<const double2*>(&lcb[v * C + 2 * j2]);
                double2 cB = *reinterpret_cast<const double2*>(&lcb[v * C + 16 + 2 * j2]);
                #pragma unroll
                for (int t = 0; t < TPT; ++t) {
                    aA[t] = fma(ca.y, zd[t][2 * j2 + 1], fma(ca.x, zd[t][2 * j2], aA[t]));
                    aB[t] = fma(cB.y, zd[t][16 + 2 * j2 + 1], fma(cB.x, zd[t][16 + 2 * j2], aB[t]));
                }
            }
            double cv = lc2[v];
            int vg = seg_base + ch + v;
            #pragma unroll
            for (int t = 0; t < TPT; ++t) {
                double s = fma(-2.0, aA[t] + aB[t], cv);
                if (s < best[t]) { best[t] = s; bi[t] = vg; }  // ascending vg: strict < keeps lowest idx on tie
            }
        }
    }
    int TP = nblk_tok * 256 * TPT;
    #pragma unroll
    for (int t = 0; t < TPT; ++t)
        if (tokv[t] < total) {
            pscore[(size_t)seg * TP + tokv[t]] = best[t];
            pidx [(size_t)seg * TP + tokv[t]] = bi[t];
        }
}

// fused stage tail: combine argmin -> gather -> bicubic up -> conv3x3 -> blend/update
//                   -> context pool -> next-z pool
__global__ __launch_bounds__(256) void stage_tail_kernel(
    const double* __restrict__ pscore, const int* __restrict__ pidx,
    const float* __restrict__ cb,
    const float* __restrict__ w, const float* __restrict__ bias,
    float* __restrict__ f_hat, float* __restrict__ f_rest,
    float* __restrict__ out, float* __restrict__ znext,
    int pn, int off, int pn2, int nseg, int TP)
{
    int bb = blockIdx.x >> 1;
    int og = (blockIdx.x & 1) * 16;
    int tid = threadIdx.x;
    int npx = pn * pn;

    __shared__ float h_s[32][257];   // hard embeddings; later overlaid by fh_s/fr_s
    __shared__ float hu_s[32][257];  // upsampled 16x16 per channel
    __shared__ int idx_s[256];
    float (*fh_s)[257] = &h_s[0];
    float (*fr_s)[257] = &h_s[16];

    // 0) combine per-segment argmins for this block's tokens
    for (int n = tid; n < npx; n += 256) {
        int tok = bb * npx + n;
        double best = pscore[tok]; int bi = pidx[tok];
        for (int s = 1; s < nseg; ++s) {
            double sc = pscore[(size_t)s * TP + tok];
            if (sc < best) { best = sc; bi = pidx[(size_t)s * TP + tok]; }  // ascending seg: tie -> lowest idx
        }
        idx_s[n] = bi;
    }
    __syncthreads();

    // 1) gather hard embeddings h[c][n] = cb[idx[n]][c]
    for (int e = tid; e < 32 * npx; e += 256) {
        int c = e & 31, n = e >> 5;
        h_s[c][n] = cb[idx_s[n] * 32 + c];
    }
    __syncthreads();

    // 2) bicubic upsample pn x pn -> 16 x 16 (identity when pn==16)
    int p = tid >> 4, q = tid & 15;
    {
        float scale = (float)pn * (1.f / 16.f);
        float srcp = (p + 0.5f) * scale - 0.5f;
        float srcq = (q + 0.5f) * scale - 0.5f;
        int fp_ = (int)floorf(srcp), fq_ = (int)floorf(srcq);
        float tp = srcp - (float)fp_, tq = srcq - (float)fq_;
        float wp[4], wq[4];
        int ip[4], iq[4];
        #pragma unroll
        for (int k = 0; k < 4; ++k) {
            wp[k] = cubicw((float)(k - 1) - tp);
            wq[k] = cubicw((float)(k - 1) - tq);
            ip[k] = min(max(fp_ + k - 1, 0), pn - 1);
            iq[k] = min(max(fq_ + k - 1, 0), pn - 1);
        }
        for (int i = 0; i < 32; ++i) {
            float s = 0.f;
            #pragma unroll
            for (int kp = 0; kp < 4; ++kp) {
                float sr = 0.f;
                #pragma unroll
                for (int kq = 0; kq < 4; ++kq)
                    sr = fmaf(wq[kq], h_s[i][ip[kp] * pn + iq[kq]], sr);
                s = fmaf(wp[kp], sr, s);
            }
            hu_s[i][tid] = s;
        }
    }
    __syncthreads();

    // 3) conv 3x3 SAME over 32 in-ch for out-ch og..og+15 (w reads are wave-uniform -> scalar loads)
    float acc[16];
    #pragma unroll
    for (int o = 0; o < 16; ++o) acc[o] = bias[og + o];
    for (int i = 0; i < 32; ++i) {
        float v[9];
        #pragma unroll
        for (int dy = 0; dy < 3; ++dy)
            #pragma unroll
            for (int dx = 0; dx < 3; ++dx) {
                int pp = p + dy - 1, qq = q + dx - 1;
                bool in = (pp >= 0) & (pp < 16) & (qq >= 0) & (qq < 16);
                v[dy * 3 + dx] = in ? hu_s[i][pp * 16 + qq] : 0.f;
            }
        #pragma unroll
        for (int o = 0; o < 16; ++o) {
            const float* wp_ = w + ((og + o) * 32 + i) * 9;
            #pragma unroll
            for (int k = 0; k < 9; ++k) acc[o] = fmaf(wp_[k], v[k], acc[o]);
        }
    }

    // 4) blend + update f_hat/f_rest, stage new values into LDS (overlay on h_s, safe: h_s dead)
    #pragma unroll
    for (int o = 0; o < 16; ++o) {
        int gi = (bb * 32 + og + o) * 256 + tid;
        float hu = hu_s[og + o][tid];
        float blend = 0.5f * hu + 0.5f * acc[o];
        float nf = f_hat[gi] + blend;
        float nr = f_rest[gi] - blend;
        f_hat[gi] = nf; f_rest[gi] = nr;
        fh_s[o][tid] = nf; fr_s[o][tid] = nr;
    }
    __syncthreads();

    // 5) context: area-pool new f_hat to pn x pn, write transposed slice of out [B,680,C]
    for (int e = tid; e < 16 * npx; e += 256) {
        int o = e & 15, n = e >> 4;
        int y = n / pn, x = n - y * pn;
        int sh = (y * HH) / pn, eh = ((y + 1) * HH + pn - 1) / pn;
        int sw = (x * HH) / pn, ew = ((x + 1) * HH + pn - 1) / pn;
        float s = 0.f;
        for (int yy = sh; yy < eh; ++yy)
            for (int xx = sw; xx < ew; ++xx) s += fh_s[o][yy * 16 + xx];
        out[((bb * 680) + off + n) * 32 + og + o] = s * (1.f / (float)((eh - sh) * (ew - sw)));
    }

    // 6) next-stage z: area-pool new f_rest to pn2 x pn2
    if (pn2 > 0) {
        int npx2 = pn2 * pn2;
        for (int e = tid; e < 16 * npx2; e += 256) {
            int o = e / npx2, n = e - o * npx2;
            int y = n / pn2, x = n - y * pn2;
            int sh = (y * HH) / pn2, eh = ((y + 1) * HH + pn2 - 1) / pn2;
            int sw = (x * HH) / pn2, ew = ((x + 1) * HH + pn2 - 1) / pn2;
            float s = 0.f;
            for (int yy = sh; yy < eh; ++yy)
                for (int xx = sw; xx < ew; ++xx) s += fr_s[o][yy * 16 + xx];
            znext[(bb * 32 + og + o) * npx2 + n] = s * (1.f / (float)((eh - sh) * (ew - sw)));
        }
    }
}

// ---------------- launch ----------------

extern "C" void kernel_launch(void* const* d_in, const int* in_sizes, int n_in,
                              void* d_out, int out_size, void* d_ws, size_t ws_size,
                              hipStream_t stream) {
    const float* feat = (const float*)d_in[0];
    const float* cb   = (const float*)d_in[1];
    const float* phiw = (const float*)d_in[2];
    const float* phib = (const float*)d_in[3];
    float* out = (float*)d_out;
    float* wsf = (float*)d_ws;

    const int NE = B * C * HH * HH; // 1048576
    float* f_rest = wsf;
    float* f_hat  = wsf + NE;
    float* zbuf   = wsf + 2 * NE;
    char*  tail   = (char*)(wsf + 3 * NE);
    double* c2     = (double*)tail;                          // 32 KB
    double* pscore = (double*)(tail + (32 << 10));           // 3.5 MB (max 409600 doubles)
    int*    pidx   = (int*)   (tail + (32 << 10) + 3670016); // 2 MB

    static const int PN_[10]   = {1, 2, 3, 4, 5, 6, 8, 10, 13, 16};
    static const int PI_[10]   = {0, 0, 1, 1, 1, 2, 2, 2, 3, 3};
    static const int OFF_[10]  = {0, 1, 5, 14, 30, 55, 91, 155, 255, 424};
    static const int NSEG_[10] = {32, 32, 32, 32, 32, 32, 32, 32, 16, 8};
    static const int TPT_[10]  = {1, 1, 1, 1, 1, 1, 2, 2, 2, 2};

    init_kernel<<<dim3((NE + 255) / 256), dim3(256), 0, stream>>>(feat, f_rest, f_hat);
    c2_kernel<<<dim3(V / 256), dim3(256), 0, stream>>>(cb, c2);
    // stage-0 z from initial f_rest (= feat)
    area_down_kernel<<<dim3((B * C + 255) / 256), dim3(256), 0, stream>>>(f_rest, zbuf, 1);

    for (int si = 0; si < 10; ++si) {
        int pn = PN_[si], npx = pn * pn;
        int tokens = B * npx;
        int tpt = TPT_[si], nseg = NSEG_[si];
        int nblk_tok = (tokens + 256 * tpt - 1) / (256 * tpt);
        int TP = nblk_tok * 256 * tpt;

        if (tpt == 1)
            quantize_scan_kernel<1><<<dim3(nblk_tok * nseg), dim3(256), 0, stream>>>(
                zbuf, cb, c2, pscore, pidx, npx, nseg, nblk_tok);
        else
            quantize_scan_kernel<2><<<dim3(nblk_tok * nseg), dim3(256), 0, stream>>>(
                zbuf, cb, c2, pscore, pidx, npx, nseg, nblk_tok);

        int pn2 = (si < 9) ? PN_[si + 1] : 0;
        stage_tail_kernel<<<dim3(B * 2), dim3(256), 0, stream>>>(
            pscore, pidx, cb, phiw + PI_[si] * C * C * 9, phib + PI_[si] * C,
            f_hat, f_rest, out, zbuf, pn, OFF_[si], pn2, nseg, TP);
    }
}

// Round 5
// 1301.166 us; speedup vs baseline: 1.0645x; 1.0645x over previous
//
#include <hip/hip_runtime.h>

#define B 128
#define C 32
#define HH 16
#define V 4096

// ---------------- helpers ----------------

__device__ __forceinline__ float cubicw(float t) {
    // PyTorch bicubic kernel, a = -0.75
    float at = fabsf(t);
    float at2 = at * at, at3 = at2 * at;
    if (at <= 1.f) return 1.25f * at3 - 2.25f * at2 + 1.f;
    if (at < 2.f)  return -0.75f * at3 + 3.75f * at2 - 6.f * at + 3.f;
    return 0.f;
}

// ---------------- kernels ----------------

__global__ void init_kernel(const float* __restrict__ feat, float* __restrict__ f_rest,
                            float* __restrict__ f_hat) {
    int i = blockIdx.x * 256 + threadIdx.x;
    if (i < B * C * HH * HH) { f_rest[i] = feat[i]; f_hat[i] = 0.f; }
}

__global__ void c2_kernel(const float* __restrict__ cb, double* __restrict__ c2) {
    int v = blockIdx.x * 256 + threadIdx.x;
    if (v < V) {
        const float* p = cb + v * C;
        double s = 0.0;
        #pragma unroll
        for (int j = 0; j < C; ++j) { double d = (double)p[j]; s = fma(d, d, s); }
        c2[v] = s;
    }
}

// area (adaptive-avg-pool) downsample: [B,C,16,16] -> [B,C,pn,pn] (stage-0 z only)
__global__ void area_down_kernel(const float* __restrict__ src, float* __restrict__ dst, int pn) {
    int i = blockIdx.x * blockDim.x + threadIdx.x;
    int npx = pn * pn;
    int total = B * C * npx;
    if (i >= total) return;
    int x = i % pn, y = (i / pn) % pn, bc = i / npx;
    int sh = (y * HH) / pn, eh = ((y + 1) * HH + pn - 1) / pn;
    int sw = (x * HH) / pn, ew = ((x + 1) * HH + pn - 1) / pn;
    const float* p = src + bc * (HH * HH);
    float s = 0.f;
    for (int yy = sh; yy < eh; ++yy)
        for (int xx = sw; xx < ew; ++xx) s += p[yy * HH + xx];
    dst[i] = s * (1.f / (float)((eh - sh) * (ew - sw)));
}

// ---- quantization scan: TPT tokens per thread over a codebook segment ----
// asm-pin forces z to stay as fp64 registers (compiler otherwise keeps fp32 and
// rematerializes v_cvt_f64_f32 per use in the inner loop -> 2.2x slowdown, R4).
template<int TPT, int CHUNK>
__global__ __launch_bounds__(256, 2) void quantize_scan_kernel(
    const float* __restrict__ z, const float* __restrict__ cb,
    const double* __restrict__ c2, double* __restrict__ pscore,
    int* __restrict__ pidx, int npx, int nseg, int nblk_tok)
{
    int total = B * npx;
    int tid = threadIdx.x;
    int tb  = blockIdx.x % nblk_tok;
    int seg = blockIdx.x / nblk_tok;
    int cps = V / nseg;
    int seg_base = seg * cps;

    double zd[TPT][C];
    int tokv[TPT];
    #pragma unroll
    for (int t = 0; t < TPT; ++t) {
        int tok = tb * (256 * TPT) + t * 256 + tid;
        tokv[t] = tok;
        int tokc = min(tok, total - 1);
        int b = tokc / npx, n = tokc - b * npx;
        #pragma unroll
        for (int c = 0; c < C; ++c) zd[t][c] = (double)z[(b * C + c) * npx + n];
    }
    // pin: opaque defs the compiler can't see through -> fp64 stays in VGPRs
    #pragma unroll
    for (int t = 0; t < TPT; ++t)
        #pragma unroll
        for (int c = 0; c < C; ++c)
            asm volatile("" : "+v"(zd[t][c]));

    __shared__ alignas(16) double lcb[CHUNK * C];
    __shared__ double lc2[CHUNK];

    double best[TPT]; int bi[TPT];
    #pragma unroll
    for (int t = 0; t < TPT; ++t) { best[t] = 1e300; bi[t] = 0; }

    for (int ch = 0; ch < cps; ch += CHUNK) {
        __syncthreads();
        const float* src = cb + (size_t)(seg_base + ch) * C;
        #pragma unroll
        for (int k = 0; k < (CHUNK * C) / 256; ++k) {
            int e = tid + k * 256;
            lcb[e] = (double)src[e];
        }
        if (tid < CHUNK) lc2[tid] = c2[seg_base + ch + tid];
        __syncthreads();

        for (int v = 0; v < CHUNK; ++v) {
            double aA[TPT], aB[TPT];
            #pragma unroll
            for (int t = 0; t < TPT; ++t) { aA[t] = 0.0; aB[t] = 0.0; }
            #pragma unroll
            for (int j2 = 0; j2 < 8; ++j2) {
                double2 ca = *reinterpret_cast<const double2*>(&lcb[v * C + 2 * j2]);
                double2 cB = *reinterpret_cast<const double2*>(&lcb[v * C + 16 + 2 * j2]);
                #pragma unroll
                for (int t = 0; t < TPT; ++t) {
                    aA[t] = fma(ca.y, zd[t][2 * j2 + 1], fma(ca.x, zd[t][2 * j2], aA[t]));
                    aB[t] = fma(cB.y, zd[t][16 + 2 * j2 + 1], fma(cB.x, zd[t][16 + 2 * j2], aB[t]));
                }
            }
            double cv = lc2[v];
            int vg = seg_base + ch + v;
            #pragma unroll
            for (int t = 0; t < TPT; ++t) {
                double s = fma(-2.0, aA[t] + aB[t], cv);
                if (s < best[t]) { best[t] = s; bi[t] = vg; }  // ascending vg: strict < keeps lowest idx on tie
            }
        }
    }
    int TP = nblk_tok * 256 * TPT;
    #pragma unroll
    for (int t = 0; t < TPT; ++t)
        if (tokv[t] < total) {
            pscore[(size_t)seg * TP + tokv[t]] = best[t];
            pidx [(size_t)seg * TP + tokv[t]] = bi[t];
        }
}

// fused stage tail: combine argmin -> gather -> bicubic up -> conv3x3 -> blend/update
//                   -> context pool -> next-z pool
__global__ __launch_bounds__(256) void stage_tail_kernel(
    const double* __restrict__ pscore, const int* __restrict__ pidx,
    const float* __restrict__ cb,
    const float* __restrict__ w, const float* __restrict__ bias,
    float* __restrict__ f_hat, float* __restrict__ f_rest,
    float* __restrict__ out, float* __restrict__ znext,
    int pn, int off, int pn2, int nseg, int TP)
{
    int bb = blockIdx.x >> 1;
    int og = (blockIdx.x & 1) * 16;
    int tid = threadIdx.x;
    int npx = pn * pn;

    __shared__ float h_s[32][257];   // hard embeddings; later overlaid by fh_s/fr_s
    __shared__ float hu_s[32][257];  // upsampled 16x16 per channel
    __shared__ int idx_s[256];
    float (*fh_s)[257] = &h_s[0];
    float (*fr_s)[257] = &h_s[16];

    // 0) combine per-segment argmins for this block's tokens
    for (int n = tid; n < npx; n += 256) {
        int tok = bb * npx + n;
        double best = pscore[tok]; int bi = pidx[tok];
        for (int s = 1; s < nseg; ++s) {
            double sc = pscore[(size_t)s * TP + tok];
            if (sc < best) { best = sc; bi = pidx[(size_t)s * TP + tok]; }  // ascending seg: tie -> lowest idx
        }
        idx_s[n] = bi;
    }
    __syncthreads();

    // 1) gather hard embeddings h[c][n] = cb[idx[n]][c]
    for (int e = tid; e < 32 * npx; e += 256) {
        int c = e & 31, n = e >> 5;
        h_s[c][n] = cb[idx_s[n] * 32 + c];
    }
    __syncthreads();

    // 2) bicubic upsample pn x pn -> 16 x 16 (identity when pn==16)
    int p = tid >> 4, q = tid & 15;
    {
        float scale = (float)pn * (1.f / 16.f);
        float srcp = (p + 0.5f) * scale - 0.5f;
        float srcq = (q + 0.5f) * scale - 0.5f;
        int fp_ = (int)floorf(srcp), fq_ = (int)floorf(srcq);
        float tp = srcp - (float)fp_, tq = srcq - (float)fq_;
        float wp[4], wq[4];
        int ip[4], iq[4];
        #pragma unroll
        for (int k = 0; k < 4; ++k) {
            wp[k] = cubicw((float)(k - 1) - tp);
            wq[k] = cubicw((float)(k - 1) - tq);
            ip[k] = min(max(fp_ + k - 1, 0), pn - 1);
            iq[k] = min(max(fq_ + k - 1, 0), pn - 1);
        }
        for (int i = 0; i < 32; ++i) {
            float s = 0.f;
            #pragma unroll
            for (int kp = 0; kp < 4; ++kp) {
                float sr = 0.f;
                #pragma unroll
                for (int kq = 0; kq < 4; ++kq)
                    sr = fmaf(wq[kq], h_s[i][ip[kp] * pn + iq[kq]], sr);
                s = fmaf(wp[kp], sr, s);
            }
            hu_s[i][tid] = s;
        }
    }
    __syncthreads();

    // 3) conv 3x3 SAME over 32 in-ch for out-ch og..og+15 (w reads are wave-uniform -> scalar loads)
    float acc[16];
    #pragma unroll
    for (int o = 0; o < 16; ++o) acc[o] = bias[og + o];
    for (int i = 0; i < 32; ++i) {
        float v[9];
        #pragma unroll
        for (int dy = 0; dy < 3; ++dy)
            #pragma unroll
            for (int dx = 0; dx < 3; ++dx) {
                int pp = p + dy - 1, qq = q + dx - 1;
                bool in = (pp >= 0) & (pp < 16) & (qq >= 0) & (qq < 16);
                v[dy * 3 + dx] = in ? hu_s[i][pp * 16 + qq] : 0.f;
            }
        #pragma unroll
        for (int o = 0; o < 16; ++o) {
            const float* wp_ = w + ((og + o) * 32 + i) * 9;
            #pragma unroll
            for (int k = 0; k < 9; ++k) acc[o] = fmaf(wp_[k], v[k], acc[o]);
        }
    }

    // 4) blend + update f_hat/f_rest, stage new values into LDS (overlay on h_s, safe: h_s dead)
    #pragma unroll
    for (int o = 0; o < 16; ++o) {
        int gi = (bb * 32 + og + o) * 256 + tid;
        float hu = hu_s[og + o][tid];
        float blend = 0.5f * hu + 0.5f * acc[o];
        float nf = f_hat[gi] + blend;
        float nr = f_rest[gi] - blend;
        f_hat[gi] = nf; f_rest[gi] = nr;
        fh_s[o][tid] = nf; fr_s[o][tid] = nr;
    }
    __syncthreads();

    // 5) context: area-pool new f_hat to pn x pn, write transposed slice of out [B,680,C]
    for (int e = tid; e < 16 * npx; e += 256) {
        int o = e & 15, n = e >> 4;
        int y = n / pn, x = n - y * pn;
        int sh = (y * HH) / pn, eh = ((y + 1) * HH + pn - 1) / pn;
        int sw = (x * HH) / pn, ew = ((x + 1) * HH + pn - 1) / pn;
        float s = 0.f;
        for (int yy = sh; yy < eh; ++yy)
            for (int xx = sw; xx < ew; ++xx) s += fh_s[o][yy * 16 + xx];
        out[((bb * 680) + off + n) * 32 + og + o] = s * (1.f / (float)((eh - sh) * (ew - sw)));
    }

    // 6) next-stage z: area-pool new f_rest to pn2 x pn2
    if (pn2 > 0) {
        int npx2 = pn2 * pn2;
        for (int e = tid; e < 16 * npx2; e += 256) {
            int o = e / npx2, n = e - o * npx2;
            int y = n / pn2, x = n - y * pn2;
            int sh = (y * HH) / pn2, eh = ((y + 1) * HH + pn2 - 1) / pn2;
            int sw = (x * HH) / pn2, ew = ((x + 1) * HH + pn2 - 1) / pn2;
            float s = 0.f;
            for (int yy = sh; yy < eh; ++yy)
                for (int xx = sw; xx < ew; ++xx) s += fr_s[o][yy * 16 + xx];
            znext[(bb * 32 + og + o) * npx2 + n] = s * (1.f / (float)((eh - sh) * (ew - sw)));
        }
    }
}

// ---------------- launch ----------------

extern "C" void kernel_launch(void* const* d_in, const int* in_sizes, int n_in,
                              void* d_out, int out_size, void* d_ws, size_t ws_size,
                              hipStream_t stream) {
    const float* feat = (const float*)d_in[0];
    const float* cb   = (const float*)d_in[1];
    const float* phiw = (const float*)d_in[2];
    const float* phib = (const float*)d_in[3];
    float* out = (float*)d_out;
    float* wsf = (float*)d_ws;

    const int NE = B * C * HH * HH; // 1048576
    float* f_rest = wsf;
    float* f_hat  = wsf + NE;
    float* zbuf   = wsf + 2 * NE;
    char*  tail   = (char*)(wsf + 3 * NE);
    double* c2     = (double*)tail;                          // 32 KB
    double* pscore = (double*)(tail + (32 << 10));           // 3.5 MB (max 409600 doubles)
    int*    pidx   = (int*)   (tail + (32 << 10) + 3670016); // 2 MB

    static const int PN_[10]   = {1, 2, 3, 4, 5, 6, 8, 10, 13, 16};
    static const int PI_[10]   = {0, 0, 1, 1, 1, 2, 2, 2, 3, 3};
    static const int OFF_[10]  = {0, 1, 5, 14, 30, 55, 91, 155, 255, 424};
    static const int NSEG_[10] = {64, 64, 64, 64, 64, 64, 32, 32, 16, 8};
    static const int TPT_[10]  = {1, 1, 1, 1, 1, 1, 2, 2, 2, 2};

    init_kernel<<<dim3((NE + 255) / 256), dim3(256), 0, stream>>>(feat, f_rest, f_hat);
    c2_kernel<<<dim3(V / 256), dim3(256), 0, stream>>>(cb, c2);
    // stage-0 z from initial f_rest (= feat)
    area_down_kernel<<<dim3((B * C + 255) / 256), dim3(256), 0, stream>>>(f_rest, zbuf, 1);

    for (int si = 0; si < 10; ++si) {
        int pn = PN_[si], npx = pn * pn;
        int tokens = B * npx;
        int tpt = TPT_[si], nseg = NSEG_[si];
        int nblk_tok = (tokens + 256 * tpt - 1) / (256 * tpt);
        int TP = nblk_tok * 256 * tpt;

        if (si < 6)
            quantize_scan_kernel<1, 64><<<dim3(nblk_tok * nseg), dim3(256), 0, stream>>>(
                zbuf, cb, c2, pscore, pidx, npx, nseg, nblk_tok);
        else
            quantize_scan_kernel<2, 128><<<dim3(nblk_tok * nseg), dim3(256), 0, stream>>>(
                zbuf, cb, c2, pscore, pidx, npx, nseg, nblk_tok);

        int pn2 = (si < 9) ? PN_[si + 1] : 0;
        stage_tail_kernel<<<dim3(B * 2), dim3(256), 0, stream>>>(
            pscore, pidx, cb, phiw + PI_[si] * C * C * 9, phib + PI_[si] * C,
            f_hat, f_rest, out, zbuf, pn, OFF_[si], pn2, nseg, TP);
    }
}